// Round 3
// baseline (660.650 us; speedup 1.0000x reference)
//
#include <hip/hip_runtime.h>
#include <math.h>

// ---------------------------------------------------------------------------
// SelfAttention R5: k_qkv 256x256 with software-pipelined fragment reads:
// inline-asm ds_read_b128 issued ONE quadrant ahead (double reg buffers),
// counted lgkmcnt + sched_barrier(0) (rule #18), counted vmcnt(4), raw
// barriers. Cures the LDS<->MFMA serialization measured in R3/R4 (28% Mfma).
// k_attn / k_proj / k_cvt / k_tab unchanged.
// ---------------------------------------------------------------------------

typedef __bf16 bf16_t;
typedef __bf16 bf16x8 __attribute__((ext_vector_type(8)));
typedef __bf16 bf16x4v __attribute__((ext_vector_type(4)));
typedef float  f32x4  __attribute__((ext_vector_type(4)));

#define B_  2
#define T_  2048
#define C_  2048
#define SLICE_ ((size_t)B_ * T_ * C_)  // 8388608

__device__ __forceinline__ void glds16(const void* g, void* l) {
  __builtin_amdgcn_global_load_lds(
      (__attribute__((address_space(1))) void*)(void*)(const_cast<void*>(g)),
      (__attribute__((address_space(3))) void*)(l), 16, 0, 0);
}

__device__ __forceinline__ unsigned ldsaddr(const void* p) {
  return (unsigned)(size_t)(__attribute__((address_space(3))) const void*)(p);
}

// ------------------------- f32 -> bf16 pack --------------------------------
__global__ __launch_bounds__(256) void k_cvt(const float4* __restrict__ in,
                                             bf16x4v* __restrict__ out, int n4) {
  int i = blockIdx.x * 256 + threadIdx.x;
  if (i < n4) {
    float4 v = in[i];
    bf16x4v o;
    o[0] = (bf16_t)v.x; o[1] = (bf16_t)v.y; o[2] = (bf16_t)v.z; o[3] = (bf16_t)v.w;
    out[i] = o;
  }
}

// ------------------------- rope cos/sin table ------------------------------
__global__ __launch_bounds__(256) void k_tab(float2* __restrict__ tab) {
  int i = blockIdx.x * 256 + threadIdx.x;  // 131072
  int t = i >> 6, j = i & 63;
  float thf = (float)pow(10000.0, -(double)(2 * j) / 128.0);
  float angf = (float)t * thf;
  double a = (double)angf;
  tab[i] = make_float2((float)cos(a), (float)sin(a));
}

// ------------------------- QKV GEMM + RoPE epilogue ------------------------
// C[m,n] = sum_k X[m,k] W[n,k]; M=4096, N=6144, K=2048.
// 256x256 tile, BK=64, 512 threads (8 waves, 2Mx4N), 128 KiB LDS (2 tiles).
// 8 intervals per 2-K-tile iteration; asm ds_read_b128 one quadrant ahead.
// LDS per tile: [256 rows][8 chunks of 16B], chunk p of row r <- global
// chunk (p ^ (r&7)). Byte layout: row stride 128, half (128 rows) = 16384.

struct FragA { bf16x8 v[4][2]; };  // 4 mf x 2 ksub
struct FragB { bf16x8 v[2][2]; };  // 2 nf x 2 ksub

__device__ __forceinline__ void stage_half(const bf16_t* __restrict__ g, int k0,
                                           bf16_t* l, int H, int tid) {
  const int wv = tid >> 6;
#pragma unroll
  for (int s = 0; s < 2; ++s) {
    int ci = s * 512 + tid;          // 0..1023 chunk index within half
    int row = ci >> 3;               // 0..127
    glds16(g + (size_t)(H * 128 + row) * 2048 + k0 + (((ci & 7) ^ (row & 7)) << 3),
           l + H * 8192 + (size_t)(s * 512 + wv * 64) * 8);
  }
}

#define LDSR(r, a, OFF) \
  asm volatile("ds_read_b128 %0, %1 offset:" #OFF : "=v"(r) : "v"(a))
#define RD_A8(F, a0, a1, B0, B1, B2, B3) do { \
  LDSR((F).v[0][0], a0, B0); LDSR((F).v[0][1], a1, B0); \
  LDSR((F).v[1][0], a0, B1); LDSR((F).v[1][1], a1, B1); \
  LDSR((F).v[2][0], a0, B2); LDSR((F).v[2][1], a1, B2); \
  LDSR((F).v[3][0], a0, B3); LDSR((F).v[3][1], a1, B3); } while (0)
#define RD_B4(F, b0, b1, C0, C1) do { \
  LDSR((F).v[0][0], b0, C0); LDSR((F).v[0][1], b1, C0); \
  LDSR((F).v[1][0], b0, C1); LDSR((F).v[1][1], b1, C1); } while (0)
#define LGKM(n) asm volatile("s_waitcnt lgkmcnt(" #n ")")
#define SCHED0() __builtin_amdgcn_sched_barrier(0)
#define BARRIER() asm volatile("s_barrier" ::: "memory")
#define VMCNT(n) asm volatile("s_waitcnt vmcnt(" #n ")" ::: "memory")

template <int HA, int HB>
__device__ __forceinline__ void mfma_q(const FragA& fa, const FragB& fb,
                                       f32x4 (&acc)[2][4][2][2]) {
  __builtin_amdgcn_s_setprio(1);
#pragma unroll
  for (int ks = 0; ks < 2; ++ks)
#pragma unroll
    for (int mf = 0; mf < 4; ++mf)
#pragma unroll
      for (int nf = 0; nf < 2; ++nf)
        acc[HA][mf][HB][nf] = __builtin_amdgcn_mfma_f32_16x16x32_bf16(
            fa.v[mf][ks], fb.v[nf][ks], acc[HA][mf][HB][nf], 0, 0, 0);
  __builtin_amdgcn_s_setprio(0);
}

__global__ __launch_bounds__(512, 1) void k_qkv(
    const bf16_t* __restrict__ X, const bf16_t* __restrict__ W,
    const float2* __restrict__ tab,
    bf16_t* __restrict__ qb, bf16_t* __restrict__ kb, bf16_t* __restrict__ vtb,
    float* __restrict__ kout, float* __restrict__ vout) {
  const int K = 2048;
  extern __shared__ char smem_raw[];   // 131072 B dynamic
  bf16_t* sm = (bf16_t*)smem_raw;
  bf16_t* AE = sm;              // byte 0
  bf16_t* AO = sm + 16384;      // byte 32768
  bf16_t* BE = sm + 32768;      // byte 65536
  bf16_t* BO = sm + 49152;      // byte 98304

  const int tid = threadIdx.x;
  const int lane = tid & 63, wv = tid >> 6;
  const int wm = wv >> 2, wn = wv & 3;          // 2M x 4N waves
  const int q4 = lane >> 4, l16 = lane & 15;

  // XCD-aware bijective swizzle over 384 blocks (384 % 8 == 0)
  const int bid = blockIdx.x;
  const int swz = (bid & 7) * 48 + (bid >> 3);
  const int m0 = (swz & 15) * 256;              // 16 m-blocks
  const int n0 = (swz >> 4) * 256;              // 24 n-blocks

  const bf16_t* Ab = X + (size_t)m0 * K;
  const bf16_t* Wb = W + (size_t)n0 * K;

  // ---- asm ds_read base addresses (bytes) --------------------------------
  const int c0 = (q4 ^ (l16 & 7)) << 4;          // ks0 swizzled chunk byte
  const int c1 = ((4 | q4) ^ (l16 & 7)) << 4;    // ks1
  const unsigned lb = ldsaddr(sm);
  const unsigned aAE0 = lb + (wm * 64 + l16) * 128 + c0;
  const unsigned aAE1 = lb + (wm * 64 + l16) * 128 + c1;
  const unsigned aAO0 = aAE0 + 32768, aAO1 = aAE1 + 32768;
  const unsigned aBE0 = lb + 65536 + (wn * 32 + l16) * 128 + c0;
  const unsigned aBE1 = lb + 65536 + (wn * 32 + l16) * 128 + c1;
  const unsigned aBO0 = aBE0 + 32768, aBO1 = aBE1 + 32768;

  f32x4 acc[2][4][2][2];
  {
    f32x4 zero4 = {0.f, 0.f, 0.f, 0.f};
#pragma unroll
    for (int ha = 0; ha < 2; ++ha)
#pragma unroll
      for (int mf = 0; mf < 4; ++mf)
#pragma unroll
        for (int hb = 0; hb < 2; ++hb)
#pragma unroll
          for (int nf = 0; nf < 2; ++nf) acc[ha][mf][hb][nf] = zero4;
  }

  FragA faA, faB;
  FragB fb0, fb1, fb2, fb3;

  // ---- prologue: stage tiles 0 (E) and 1 (O) fully; pre-read Q0(E) regs ---
  stage_half(Ab, 0, AE, 0, tid);
  stage_half(Ab, 0, AE, 1, tid);
  stage_half(Wb, 0, BE, 0, tid);
  stage_half(Wb, 0, BE, 1, tid);
  stage_half(Ab, 64, AO, 0, tid);
  stage_half(Ab, 64, AO, 1, tid);
  stage_half(Wb, 64, BO, 0, tid);
  stage_half(Wb, 64, BO, 1, tid);
  VMCNT(8);          // E fully landed (O's 8 may be in flight)
  BARRIER();
  RD_A8(faA, aAE0, aAE1, 0, 2048, 4096, 6144);   // A(E)h0
  RD_B4(fb0, aBE0, aBE1, 0, 2048);               // B(E)h0
  RD_B4(fb1, aBE0, aBE1, 16384, 18432);          // B(E)h1

  // ---- main loop: 16 iters, 2 K-tiles per iter ----------------------------
#pragma unroll 1
  for (int t = 0; t < 16; ++t) {
    const int kE2 = (t * 128 + 128) & 2047;  // next even tile (wrap: harmless)
    const int kO2 = (t * 128 + 192) & 2047;  // next odd tile

    // I1: Q(0,0)E [faA,fb0]
    LGKM(4); SCHED0();
    mfma_q<0, 0>(faA, fb0, acc);
    BARRIER();
    // I2: Q(0,1)E [faA,fb1]; read A(E)h1->faB; stage E' Ah0,Bh0
    RD_A8(faB, aAE0, aAE1, 16384, 18432, 20480, 22528);
    stage_half(Ab, kE2, AE, 0, tid);
    stage_half(Wb, kE2, BE, 0, tid);
    LGKM(8); SCHED0();
    mfma_q<0, 1>(faA, fb1, acc);
    VMCNT(4);          // prev-iter O stages (this iter's O tile) landed
    BARRIER();
    // I3: Q(1,1)E [faB,fb1]; read A(O)h0->faA, B(O)h0->fb2; stage E' Bh1
    RD_A8(faA, aAO0, aAO1, 0, 2048, 4096, 6144);
    RD_B4(fb2, aBO0, aBO1, 0, 2048);
    stage_half(Wb, kE2, BE, 1, tid);
    LGKM(12); SCHED0();
    mfma_q<1, 1>(faB, fb1, acc);
    BARRIER();
    // I4: Q(1,0)E [faB,fb0]; read B(O)h1->fb3; stage E' Ah1
    RD_B4(fb3, aBO0, aBO1, 16384, 18432);
    stage_half(Ab, kE2, AE, 1, tid);
    mfma_q<1, 0>(faB, fb0, acc);   // operands covered by I3's wait
    BARRIER();
    // I5: Q(0,0)O [faA,fb2]; read A(O)h1->faB
    RD_A8(faB, aAO0, aAO1, 16384, 18432, 20480, 22528);
    LGKM(12); SCHED0();
    mfma_q<0, 0>(faA, fb2, acc);
    BARRIER();
    // I6: Q(0,1)O [faA,fb3]; stage O' Ah0,Bh0
    stage_half(Ab, kO2, AO, 0, tid);
    stage_half(Wb, kO2, BO, 0, tid);
    LGKM(8); SCHED0();
    mfma_q<0, 1>(faA, fb3, acc);
    VMCNT(4);          // E' stages (I2..I4) landed
    BARRIER();
    // I7: Q(1,1)O [faB,fb3]; read A(E')h0->faA, B(E')h0->fb0; stage O' Bh1
    RD_A8(faA, aAE0, aAE1, 0, 2048, 4096, 6144);
    RD_B4(fb0, aBE0, aBE1, 0, 2048);
    stage_half(Wb, kO2, BO, 1, tid);
    LGKM(12); SCHED0();
    mfma_q<1, 1>(faB, fb3, acc);
    BARRIER();
    // I8: Q(1,0)O [faB,fb2]; read B(E')h1->fb1; stage O' Ah1
    RD_B4(fb1, aBE0, aBE1, 16384, 18432);
    stage_half(Ab, kO2, AO, 1, tid);
    mfma_q<1, 0>(faB, fb2, acc);   // operands covered by I7's wait
    BARRIER();
  }

  asm volatile("s_waitcnt vmcnt(0) lgkmcnt(0)" ::: "memory");
  __syncthreads();  // smem reusable for epilogue

  // ---- epilogue ------------------------------------------------------------
  const int sec = n0 >> 11;                  // 0=q, 1=k, 2=v (block-uniform)
  const int t0 = m0 & 2047, bb = m0 >> 11, h0 = (n0 & 2047) >> 7;

  if (sec < 2) {
    // two passes of 128 rows through LDS (stride 264), RoPE applied
#pragma unroll
    for (int ha = 0; ha < 2; ++ha) {
      if (ha) __syncthreads();
#pragma unroll
      for (int mf = 0; mf < 4; ++mf)
#pragma unroll
        for (int hb = 0; hb < 2; ++hb)
#pragma unroll
          for (int nf = 0; nf < 2; ++nf)
#pragma unroll
            for (int r = 0; r < 4; ++r) {
              int mlr = wm * 64 + mf * 16 + q4 * 4 + r;        // row in half
              int d2  = hb * 128 + wn * 32 + nf * 16 + l16;    // 0..255
              int d   = d2 & 127;
              float val = acc[ha][mf][hb][nf][r];
              float partner = __shfl_xor(val, 1);
              float2 cs = tab[(t0 + ha * 128 + mlr) * 64 + (d >> 1)];
              float rv = (d & 1) ? (val * cs.x + partner * cs.y)
                                 : (val * cs.x - partner * cs.y);
              if (sec == 0) rv *= 0.08838834764831845f;  // fold 1/sqrt(hd)
              else kout[(size_t)(m0 + ha * 128 + mlr) * 2048 +
                        (h0 + hb) * 128 + d] = val;
              sm[mlr * 264 + d2] = (bf16_t)rv;
            }
      __syncthreads();
      bf16_t* dst = (sec == 0 ? qb : kb);
#pragma unroll
      for (int i = 0; i < 8; ++i) {
        int ci = i * 512 + tid;                 // 0..4095
        int mlr = ci >> 5, cc = (ci & 31) * 8;
        int hs = cc >> 7, d = cc & 127;
        *(bf16x8*)(dst +
                   ((size_t)(bb * 16 + h0 + hs) * 2048 + t0 + ha * 128 + mlr) * 128 +
                   d) = *(const bf16x8*)&sm[mlr * 264 + cc];
      }
    }
  } else {
    // v: direct f32 out + 128d x 256t transpose via LDS per head
#pragma unroll
    for (int hb = 0; hb < 2; ++hb) {
      if (hb) __syncthreads();
#pragma unroll
      for (int ha = 0; ha < 2; ++ha)
#pragma unroll
        for (int mf = 0; mf < 4; ++mf)
#pragma unroll
          for (int nf = 0; nf < 2; ++nf)
#pragma unroll
            for (int r = 0; r < 4; ++r) {
              int ml = ha * 128 + wm * 64 + mf * 16 + q4 * 4 + r;  // 0..255
              int d2 = hb * 128 + wn * 32 + nf * 16 + l16;
              int d  = d2 & 127;
              float val = acc[ha][mf][hb][nf][r];
              vout[((size_t)(bb * 16 + h0 + hb) * 2048 + t0 + ml) * 128 + d] = val;
              sm[d * 264 + ml] = (bf16_t)val;   // transpose in LDS
            }
      __syncthreads();
#pragma unroll
      for (int i = 0; i < 8; ++i) {
        int ci = i * 512 + tid;                 // 0..4095
        int dr = ci >> 5, cc = (ci & 31) * 8;
        *(bf16x8*)(vtb +
                   ((size_t)((bb * 16 + h0 + hb) * 128 + dr)) * 2048 + t0 + cc) =
            *(const bf16x8*)&sm[dr * 264 + cc];
      }
    }
  }
}

// ------------------------- flash attention ---------------------------------
// block = (b,h) x 128 queries, 4 waves x 32 queries. KT=64. Q in registers.
// No-max softmax: O_unnorm += exp(s) V; l += sum exp(s); normalize at end.
__global__ __launch_bounds__(256, 2) void k_attn(
    const bf16_t* __restrict__ qb, const bf16_t* __restrict__ kb,
    const bf16_t* __restrict__ vtb, bf16_t* __restrict__ ob) {
  __shared__ alignas(16) bf16_t Ps[128 * 80];   // P tile, stride 80
  __shared__ alignas(16) bf16_t Ks[64 * 128];   // swizzled
  __shared__ alignas(16) bf16_t Vts[128 * 64];  // swizzled, [d][key]

  const int tid = threadIdx.x;
  const int lane = tid & 63, wv = tid >> 6;
  const int q4 = lane >> 4, l16 = lane & 15;
  const int bh = blockIdx.x >> 4;
  const int q0 = (blockIdx.x & 15) * 128;

  const bf16_t* Qg = qb + (size_t)bh * T_ * 128 + (size_t)q0 * 128;
  const bf16_t* Kg = kb + (size_t)bh * T_ * 128;
  const bf16_t* Vg = vtb + (size_t)bh * 128 * T_;

  // Q frags straight from global (one-time, pre-scaled by 1/sqrt(hd))
  bf16x8 qa[2][4];
#pragma unroll
  for (int mf = 0; mf < 2; ++mf)
#pragma unroll
    for (int kf = 0; kf < 4; ++kf)
      qa[mf][kf] = *(const bf16x8*)(Qg + (size_t)(wv * 32 + mf * 16 + l16) * 128 +
                                    kf * 32 + q4 * 8);

  f32x4 zero4 = {0.f, 0.f, 0.f, 0.f};
  float lrow[2][4];
  f32x4 oacc[2][8];
#pragma unroll
  for (int mf = 0; mf < 2; ++mf) {
#pragma unroll
    for (int r = 0; r < 4; ++r) lrow[mf][r] = 0.f;
#pragma unroll
    for (int nf = 0; nf < 8; ++nf) oacc[mf][nf] = zero4;
  }

  for (int key0 = 0; key0 < T_; key0 += 64) {
    __syncthreads();
#pragma unroll
    for (int i = 0; i < 4; ++i) {  // Ks: 64 rows x 16 chunks, swizzled
      int ci = i * 256 + tid;
      glds16(Kg + (size_t)(key0 + (ci >> 4)) * 128 +
                 (((ci & 15) ^ ((ci >> 4) & 7)) << 3),
             &Ks[(i * 256 + wv * 64) * 8]);
    }
#pragma unroll
    for (int i = 0; i < 4; ++i) {  // Vts: 128 rows(d) x 8 chunks, swizzled
      int ci = i * 256 + tid;
      glds16(Vg + (size_t)(ci >> 3) * T_ + key0 +
                 (((ci & 7) ^ ((ci >> 3) & 7)) << 3),
             &Vts[(i * 256 + wv * 64) * 8]);
    }
    __syncthreads();

    // S = Q K^T (pre-scaled)
    f32x4 sacc[2][4];
#pragma unroll
    for (int mf = 0; mf < 2; ++mf)
#pragma unroll
      for (int nf = 0; nf < 4; ++nf) sacc[mf][nf] = zero4;
#pragma unroll
    for (int kf = 0; kf < 4; ++kf) {
      bf16x8 bfrag[4];
#pragma unroll
      for (int nf = 0; nf < 4; ++nf)
        bfrag[nf] = *(const bf16x8*)&Ks[(nf * 16 + l16) * 128 +
                                        ((((kf << 2) | q4) ^ (l16 & 7)) << 3)];
#pragma unroll
      for (int mf = 0; mf < 2; ++mf)
#pragma unroll
        for (int nf = 0; nf < 4; ++nf)
          sacc[mf][nf] = __builtin_amdgcn_mfma_f32_16x16x32_bf16(
              qa[mf][kf], bfrag[nf], sacc[mf][nf], 0, 0, 0);
    }

    // exp + P to LDS; per-lane partial row sums (reduced after key loop)
#pragma unroll
    for (int mf = 0; mf < 2; ++mf) {
#pragma unroll
      for (int r = 0; r < 4; ++r) {
        float p0 = __expf(sacc[mf][0][r]);
        float p1 = __expf(sacc[mf][1][r]);
        float p2 = __expf(sacc[mf][2][r]);
        float p3 = __expf(sacc[mf][3][r]);
        int prow = wv * 32 + mf * 16 + q4 * 4 + r;
        Ps[prow * 80 + 0 + l16]  = (bf16_t)p0;
        Ps[prow * 80 + 16 + l16] = (bf16_t)p1;
        Ps[prow * 80 + 32 + l16] = (bf16_t)p2;
        Ps[prow * 80 + 48 + l16] = (bf16_t)p3;
        lrow[mf][r] += (p0 + p1) + (p2 + p3);
      }
    }

    // O += P V
#pragma unroll
    for (int kf2 = 0; kf2 < 2; ++kf2) {
      bf16x8 pa[2], vb[8];
#pragma unroll
      for (int mf = 0; mf < 2; ++mf)
        pa[mf] = *(const bf16x8*)&Ps[(wv * 32 + mf * 16 + l16) * 80 +
                                     kf2 * 32 + q4 * 8];
#pragma unroll
      for (int nf = 0; nf < 8; ++nf)
        vb[nf] = *(const bf16x8*)&Vts[(nf * 16 + l16) * 64 +
                                      ((((kf2 << 2) | q4) ^ (l16 & 7)) << 3)];
#pragma unroll
      for (int mf = 0; mf < 2; ++mf)
#pragma unroll
        for (int nf = 0; nf < 8; ++nf)
          oacc[mf][nf] = __builtin_amdgcn_mfma_f32_16x16x32_bf16(
              pa[mf], vb[nf], oacc[mf][nf], 0, 0, 0);
    }
  }

  // reduce l across the 16-lane row group, then normalize + store
  const int b = bh >> 4, h = bh & 15;
#pragma unroll
  for (int mf = 0; mf < 2; ++mf) {
#pragma unroll
    for (int r = 0; r < 4; ++r) {
      float l = lrow[mf][r];
      l += __shfl_xor(l, 1);
      l += __shfl_xor(l, 2);
      l += __shfl_xor(l, 4);
      l += __shfl_xor(l, 8);
      float inv = 1.f / l;
      int t = q0 + wv * 32 + mf * 16 + q4 * 4 + r;
      size_t base = ((size_t)b * 2048 + t) * 2048 + h * 128;
#pragma unroll
      for (int nf = 0; nf < 8; ++nf)
        ob[base + nf * 16 + l16] = (bf16_t)(oacc[mf][nf][r] * inv);
    }
  }
}

// ------------------------- projection GEMM ---------------------------------
__global__ __launch_bounds__(256, 2) void k_proj(
    const bf16_t* __restrict__ O, const bf16_t* __restrict__ Wp,
    float* __restrict__ Y) {
  const int K = 2048;
  __shared__ alignas(16) bf16_t As[128 * 64];
  __shared__ alignas(16) bf16_t Bs[128 * 64];
  const int tid = threadIdx.x;
  const int lane = tid & 63, wv = tid >> 6;
  const int wm = wv >> 1, wn = wv & 1;
  const int q4 = lane >> 4, l16 = lane & 15;
  const int m0 = blockIdx.x * 128, n0 = blockIdx.y * 128;

  const bf16_t* Ab = O + (size_t)m0 * K;
  const bf16_t* Wb = Wp + (size_t)n0 * K;

  f32x4 zero4 = {0.f, 0.f, 0.f, 0.f};
  f32x4 acc[4][4];
#pragma unroll
  for (int i = 0; i < 4; ++i)
#pragma unroll
    for (int j = 0; j < 4; ++j) acc[i][j] = zero4;

  for (int k0 = 0; k0 < K; k0 += 64) {
    __syncthreads();
#pragma unroll
    for (int i = 0; i < 4; ++i) {
      int ci = i * 256 + tid;
      glds16(Ab + (size_t)(ci >> 3) * K + k0 + (((ci & 7) ^ ((ci >> 3) & 7)) << 3),
             &As[(i * 256 + wv * 64) * 8]);
    }
#pragma unroll
    for (int i = 0; i < 4; ++i) {
      int ci = i * 256 + tid;
      glds16(Wb + (size_t)(ci >> 3) * K + k0 + (((ci & 7) ^ ((ci >> 3) & 7)) << 3),
             &Bs[(i * 256 + wv * 64) * 8]);
    }
    __syncthreads();
#pragma unroll
    for (int kk = 0; kk < 2; ++kk) {
      bf16x8 afrag[4], bfrag[4];
#pragma unroll
      for (int mf = 0; mf < 4; ++mf)
        afrag[mf] = *(const bf16x8*)&As[(wm * 64 + mf * 16 + l16) * 64 +
                                        ((((kk << 2) | q4) ^ (l16 & 7)) << 3)];
#pragma unroll
      for (int nf = 0; nf < 4; ++nf)
        bfrag[nf] = *(const bf16x8*)&Bs[(wn * 64 + nf * 16 + l16) * 64 +
                                        ((((kk << 2) | q4) ^ (l16 & 7)) << 3)];
#pragma unroll
      for (int mf = 0; mf < 4; ++mf)
#pragma unroll
        for (int nf = 0; nf < 4; ++nf)
          acc[mf][nf] = __builtin_amdgcn_mfma_f32_16x16x32_bf16(
              afrag[mf], bfrag[nf], acc[mf][nf], 0, 0, 0);
    }
  }
#pragma unroll
  for (int mf = 0; mf < 4; ++mf)
#pragma unroll
    for (int nf = 0; nf < 4; ++nf)
#pragma unroll
      for (int r = 0; r < 4; ++r) {
        int m = m0 + wm * 64 + mf * 16 + q4 * 4 + r;
        int n = n0 + wn * 64 + nf * 16 + l16;
        Y[(size_t)m * 2048 + n] = acc[mf][nf][r];
      }
}

// ------------------------- launch ------------------------------------------
extern "C" void kernel_launch(void* const* d_in, const int* in_sizes, int n_in,
                              void* d_out, int out_size, void* d_ws, size_t ws_size,
                              hipStream_t stream) {
  const float* x = (const float*)d_in[0];
  const float* wqkv = (const float*)d_in[1];
  const float* wproj = (const float*)d_in[2];

  float* y = (float*)d_out;
  float* kout = y + SLICE_;
  float* vout = y + 2 * SLICE_;

  char* w = (char*)d_ws;
  bf16_t* xb = (bf16_t*)w;      w += SLICE_ * 2;
  bf16_t* wqkvb = (bf16_t*)w;   w += (size_t)12582912 * 2;
  bf16_t* wprojb = (bf16_t*)w;  w += (size_t)4194304 * 2;
  bf16_t* qb = (bf16_t*)w;      w += SLICE_ * 2;  // scaled+rope'd q, (B,H,T,hd)
  bf16_t* kb = (bf16_t*)w;      w += SLICE_ * 2;  // rope'd k, (B,H,T,hd)
  bf16_t* vtb = (bf16_t*)w;     w += SLICE_ * 2;  // v, (B,H,hd,T)
  bf16_t* ob = (bf16_t*)w;      w += SLICE_ * 2;  // attn out, (B,T,C)
  float2* tab = (float2*)w;     w += (size_t)131072 * 8;
  (void)ws_size; (void)in_sizes; (void)n_in; (void)out_size;

  static int smem_set = 0;
  if (!smem_set) {
    hipFuncSetAttribute((const void*)k_qkv,
                        hipFuncAttributeMaxDynamicSharedMemorySize, 131072);
    smem_set = 1;
  }

  k_cvt<<<8192, 256, 0, stream>>>((const float4*)x, (bf16x4v*)xb, 2097152);
  k_cvt<<<12288, 256, 0, stream>>>((const float4*)wqkv, (bf16x4v*)wqkvb, 3145728);
  k_cvt<<<4096, 256, 0, stream>>>((const float4*)wproj, (bf16x4v*)wprojb, 1048576);
  k_tab<<<512, 256, 0, stream>>>(tab);

  k_qkv<<<384, 512, 131072, stream>>>(xb, wqkvb, tab, qb, kb, vtb, kout, vout);
  k_attn<<<512, 256, 0, stream>>>(qb, kb, vtb, ob);
  dim3 gp(32, 16);
  k_proj<<<gp, 256, 0, stream>>>(ob, wprojb, y);
}

// Round 4
// 402.262 us; speedup vs baseline: 1.6423x; 1.6423x over previous
//
#include <hip/hip_runtime.h>
#include <math.h>

// ---------------------------------------------------------------------------
// SelfAttention R6: full revert of k_qkv to the proven R2 128x128 structure
// (8-phase ports R3-R5 all regressed: lockstep serialization / reg spills).
// One change vs R2: k_attn block->XCD grouping so the 16 q-chunk blocks of
// each (b,h) land on one XCD -> K/V (1MB/bh) stays L2-resident; HBM K/V
// traffic ~512MB -> ~32MB.
// ---------------------------------------------------------------------------

typedef __bf16 bf16_t;
typedef __bf16 bf16x8 __attribute__((ext_vector_type(8)));
typedef __bf16 bf16x4v __attribute__((ext_vector_type(4)));
typedef float  f32x4  __attribute__((ext_vector_type(4)));

#define B_  2
#define T_  2048
#define C_  2048
#define SLICE_ ((size_t)B_ * T_ * C_)  // 8388608

__device__ __forceinline__ void glds16(const void* g, void* l) {
  __builtin_amdgcn_global_load_lds(
      (__attribute__((address_space(1))) void*)(void*)(const_cast<void*>(g)),
      (__attribute__((address_space(3))) void*)(l), 16, 0, 0);
}

// ------------------------- f32 -> bf16 pack --------------------------------
__global__ __launch_bounds__(256) void k_cvt(const float4* __restrict__ in,
                                             bf16x4v* __restrict__ out, int n4) {
  int i = blockIdx.x * 256 + threadIdx.x;
  if (i < n4) {
    float4 v = in[i];
    bf16x4v o;
    o[0] = (bf16_t)v.x; o[1] = (bf16_t)v.y; o[2] = (bf16_t)v.z; o[3] = (bf16_t)v.w;
    out[i] = o;
  }
}

// ------------------------- rope cos/sin table ------------------------------
__global__ __launch_bounds__(256) void k_tab(float2* __restrict__ tab) {
  int i = blockIdx.x * 256 + threadIdx.x;  // 131072
  int t = i >> 6, j = i & 63;
  float thf = (float)pow(10000.0, -(double)(2 * j) / 128.0);
  float angf = (float)t * thf;
  double a = (double)angf;
  tab[i] = make_float2((float)cos(a), (float)sin(a));
}

// ------------------------- QKV GEMM + RoPE epilogue ------------------------
// C[m,n] = sum_k X[m,k] W[n,k]; M=4096, N=6144, K=2048. 128x128 tile, BK=64.
// LDS tiles xor-swizzled: LDS[row, c'] = global[row, c' ^ (row&7)] (16B chunks)
__global__ __launch_bounds__(256, 2) void k_qkv(
    const bf16_t* __restrict__ X, const bf16_t* __restrict__ W,
    const float2* __restrict__ tab,
    bf16_t* __restrict__ qb, bf16_t* __restrict__ kb, bf16_t* __restrict__ vtb,
    float* __restrict__ kout, float* __restrict__ vout) {
  const int K = 2048;
  __shared__ alignas(16) bf16_t smem[17408];  // As|Bs (16384) U epilogue 128x136
  bf16_t* As = smem;
  bf16_t* Bs = smem + 8192;
  const int tid = threadIdx.x;
  const int lane = tid & 63, wv = tid >> 6;
  const int wm = wv >> 1, wn = wv & 1;
  const int q4 = lane >> 4, l16 = lane & 15;
  const int m0 = blockIdx.x * 128, n0 = blockIdx.y * 128;

  const bf16_t* Ab = X + (size_t)m0 * K;
  const bf16_t* Wb = W + (size_t)n0 * K;

  f32x4 zero4 = {0.f, 0.f, 0.f, 0.f};
  f32x4 acc[4][4];
#pragma unroll
  for (int i = 0; i < 4; ++i)
#pragma unroll
    for (int j = 0; j < 4; ++j) acc[i][j] = zero4;

  for (int k0 = 0; k0 < K; k0 += 64) {
    __syncthreads();
#pragma unroll
    for (int i = 0; i < 4; ++i) {  // 128 rows x 8 chunks
      int ci = i * 256 + tid;
      glds16(Ab + (size_t)(ci >> 3) * K + k0 + (((ci & 7) ^ ((ci >> 3) & 7)) << 3),
             &As[(i * 256 + wv * 64) * 8]);
    }
#pragma unroll
    for (int i = 0; i < 4; ++i) {
      int ci = i * 256 + tid;
      glds16(Wb + (size_t)(ci >> 3) * K + k0 + (((ci & 7) ^ ((ci >> 3) & 7)) << 3),
             &Bs[(i * 256 + wv * 64) * 8]);
    }
    __syncthreads();
#pragma unroll
    for (int kk = 0; kk < 2; ++kk) {
      bf16x8 afrag[4], bfrag[4];
#pragma unroll
      for (int mf = 0; mf < 4; ++mf)
        afrag[mf] = *(const bf16x8*)&As[(wm * 64 + mf * 16 + l16) * 64 +
                                        ((((kk << 2) | q4) ^ (l16 & 7)) << 3)];
#pragma unroll
      for (int nf = 0; nf < 4; ++nf)
        bfrag[nf] = *(const bf16x8*)&Bs[(wn * 64 + nf * 16 + l16) * 64 +
                                        ((((kk << 2) | q4) ^ (l16 & 7)) << 3)];
#pragma unroll
      for (int mf = 0; mf < 4; ++mf)
#pragma unroll
        for (int nf = 0; nf < 4; ++nf)
          acc[mf][nf] = __builtin_amdgcn_mfma_f32_16x16x32_bf16(
              afrag[mf], bfrag[nf], acc[mf][nf], 0, 0, 0);
    }
  }

  __syncthreads();  // smem reuse for epilogue staging
  const int sec = n0 >> 11;  // 0=q, 1=k, 2=v (block-uniform)
  const int t0 = m0 & 2047, bb = m0 >> 11, h = (n0 & 2047) >> 7;

  if (sec < 2) {
#pragma unroll
    for (int mf = 0; mf < 4; ++mf)
#pragma unroll
      for (int nf = 0; nf < 4; ++nf)
#pragma unroll
        for (int r = 0; r < 4; ++r) {
          int ml = wm * 64 + mf * 16 + q4 * 4 + r;
          int d = wn * 64 + nf * 16 + l16;
          float val = acc[mf][nf][r];
          float partner = __shfl_xor(val, 1);
          float2 cs = tab[(t0 + ml) * 64 + (d >> 1)];
          float rv = (d & 1) ? (val * cs.x + partner * cs.y)
                             : (val * cs.x - partner * cs.y);
          if (sec == 0) rv *= 0.08838834764831845f;  // fold 1/sqrt(hd) into q
          else kout[(size_t)(m0 + ml) * 2048 + h * 128 + d] = val;
          smem[ml * 136 + d] = (bf16_t)rv;
        }
    __syncthreads();
    bf16_t* dst = (sec == 0 ? qb : kb);
    size_t gbase = ((size_t)(bb * 16 + h) * 2048 + t0) * 128;
#pragma unroll
    for (int i = 0; i < 8; ++i) {
      int ci = i * 256 + tid, ml = ci >> 4, cc = (ci & 15) * 8;
      *(bf16x8*)(dst + gbase + (size_t)ml * 128 + cc) =
          *(const bf16x8*)&smem[ml * 136 + cc];
    }
  } else {
#pragma unroll
    for (int mf = 0; mf < 4; ++mf)
#pragma unroll
      for (int nf = 0; nf < 4; ++nf)
#pragma unroll
        for (int r = 0; r < 4; ++r) {
          int ml = wm * 64 + mf * 16 + q4 * 4 + r;
          int d = wn * 64 + nf * 16 + l16;
          float val = acc[mf][nf][r];
          vout[((size_t)(bb * 16 + h) * 2048 + t0 + ml) * 128 + d] = val;
          smem[d * 136 + ml] = (bf16_t)val;  // transpose in LDS
        }
    __syncthreads();
#pragma unroll
    for (int i = 0; i < 8; ++i) {
      int ci = i * 256 + tid, dr = ci >> 4, cc = (ci & 15) * 8;
      *(bf16x8*)(vtb + ((size_t)((bb * 16 + h) * 128 + dr)) * 2048 + t0 + cc) =
          *(const bf16x8*)&smem[dr * 136 + cc];
    }
  }
}

// ------------------------- flash attention ---------------------------------
// block = (b,h) x 128 queries, 4 waves x 32 queries. KT=64. Q in registers.
// No-max softmax: O_unnorm += exp(s) V; l += sum exp(s); normalize at end.
// Block->XCD grouping: XCD (bid&7) owns bh in {4x..4x+3}; all 512 blocks
// co-resident (2/CU) -> per-XCD K/V working set = 4MB = L2.
__global__ __launch_bounds__(256, 2) void k_attn(
    const bf16_t* __restrict__ qb, const bf16_t* __restrict__ kb,
    const bf16_t* __restrict__ vtb, bf16_t* __restrict__ ob) {
  __shared__ alignas(16) bf16_t Ps[128 * 80];   // P tile, stride 80
  __shared__ alignas(16) bf16_t Ks[64 * 128];   // swizzled
  __shared__ alignas(16) bf16_t Vts[128 * 64];  // swizzled, [d][key]

  const int tid = threadIdx.x;
  const int lane = tid & 63, wv = tid >> 6;
  const int q4 = lane >> 4, l16 = lane & 15;
  // XCD grouping: hardware round-robins blockIdx across 8 XCDs.
  const int bid = blockIdx.x;
  const int xcd = bid & 7, j = bid >> 3;        // j in 0..63
  const int bh = xcd * 4 + (j & 3);             // 4 bh per XCD
  const int q0 = (j >> 2) * 128;                // 16 q-chunks per bh

  const bf16_t* Qg = qb + (size_t)bh * T_ * 128 + (size_t)q0 * 128;
  const bf16_t* Kg = kb + (size_t)bh * T_ * 128;
  const bf16_t* Vg = vtb + (size_t)bh * 128 * T_;

  // Q frags straight from global (one-time, pre-scaled by 1/sqrt(hd))
  bf16x8 qa[2][4];
#pragma unroll
  for (int mf = 0; mf < 2; ++mf)
#pragma unroll
    for (int kf = 0; kf < 4; ++kf)
      qa[mf][kf] = *(const bf16x8*)(Qg + (size_t)(wv * 32 + mf * 16 + l16) * 128 +
                                    kf * 32 + q4 * 8);

  f32x4 zero4 = {0.f, 0.f, 0.f, 0.f};
  float lrow[2][4];
  f32x4 oacc[2][8];
#pragma unroll
  for (int mf = 0; mf < 2; ++mf) {
#pragma unroll
    for (int r = 0; r < 4; ++r) lrow[mf][r] = 0.f;
#pragma unroll
    for (int nf = 0; nf < 8; ++nf) oacc[mf][nf] = zero4;
  }

  for (int key0 = 0; key0 < T_; key0 += 64) {
    __syncthreads();
#pragma unroll
    for (int i = 0; i < 4; ++i) {  // Ks: 64 rows x 16 chunks, swizzled
      int ci = i * 256 + tid;
      glds16(Kg + (size_t)(key0 + (ci >> 4)) * 128 +
                 (((ci & 15) ^ ((ci >> 4) & 7)) << 3),
             &Ks[(i * 256 + wv * 64) * 8]);
    }
#pragma unroll
    for (int i = 0; i < 4; ++i) {  // Vts: 128 rows(d) x 8 chunks, swizzled
      int ci = i * 256 + tid;
      glds16(Vg + (size_t)(ci >> 3) * T_ + key0 +
                 (((ci & 7) ^ ((ci >> 3) & 7)) << 3),
             &Vts[(i * 256 + wv * 64) * 8]);
    }
    __syncthreads();

    // S = Q K^T (pre-scaled)
    f32x4 sacc[2][4];
#pragma unroll
    for (int mf = 0; mf < 2; ++mf)
#pragma unroll
      for (int nf = 0; nf < 4; ++nf) sacc[mf][nf] = zero4;
#pragma unroll
    for (int kf = 0; kf < 4; ++kf) {
      bf16x8 bfrag[4];
#pragma unroll
      for (int nf = 0; nf < 4; ++nf)
        bfrag[nf] = *(const bf16x8*)&Ks[(nf * 16 + l16) * 128 +
                                        ((((kf << 2) | q4) ^ (l16 & 7)) << 3)];
#pragma unroll
      for (int mf = 0; mf < 2; ++mf)
#pragma unroll
        for (int nf = 0; nf < 4; ++nf)
          sacc[mf][nf] = __builtin_amdgcn_mfma_f32_16x16x32_bf16(
              qa[mf][kf], bfrag[nf], sacc[mf][nf], 0, 0, 0);
    }

    // exp + P to LDS; per-lane partial row sums (reduced after key loop)
#pragma unroll
    for (int mf = 0; mf < 2; ++mf) {
#pragma unroll
      for (int r = 0; r < 4; ++r) {
        float p0 = __expf(sacc[mf][0][r]);
        float p1 = __expf(sacc[mf][1][r]);
        float p2 = __expf(sacc[mf][2][r]);
        float p3 = __expf(sacc[mf][3][r]);
        int prow = wv * 32 + mf * 16 + q4 * 4 + r;
        Ps[prow * 80 + 0 + l16]  = (bf16_t)p0;
        Ps[prow * 80 + 16 + l16] = (bf16_t)p1;
        Ps[prow * 80 + 32 + l16] = (bf16_t)p2;
        Ps[prow * 80 + 48 + l16] = (bf16_t)p3;
        lrow[mf][r] += (p0 + p1) + (p2 + p3);
      }
    }

    // O += P V
#pragma unroll
    for (int kf2 = 0; kf2 < 2; ++kf2) {
      bf16x8 pa[2], vb[8];
#pragma unroll
      for (int mf = 0; mf < 2; ++mf)
        pa[mf] = *(const bf16x8*)&Ps[(wv * 32 + mf * 16 + l16) * 80 +
                                     kf2 * 32 + q4 * 8];
#pragma unroll
      for (int nf = 0; nf < 8; ++nf)
        vb[nf] = *(const bf16x8*)&Vts[(nf * 16 + l16) * 64 +
                                      ((((kf2 << 2) | q4) ^ (l16 & 7)) << 3)];
#pragma unroll
      for (int mf = 0; mf < 2; ++mf)
#pragma unroll
        for (int nf = 0; nf < 8; ++nf)
          oacc[mf][nf] = __builtin_amdgcn_mfma_f32_16x16x32_bf16(
              pa[mf], vb[nf], oacc[mf][nf], 0, 0, 0);
    }
  }

  // reduce l across the 16-lane row group, then normalize + store
  const int b = bh >> 4, h = bh & 15;
#pragma unroll
  for (int mf = 0; mf < 2; ++mf) {
#pragma unroll
    for (int r = 0; r < 4; ++r) {
      float l = lrow[mf][r];
      l += __shfl_xor(l, 1);
      l += __shfl_xor(l, 2);
      l += __shfl_xor(l, 4);
      l += __shfl_xor(l, 8);
      float inv = 1.f / l;
      int t = q0 + wv * 32 + mf * 16 + q4 * 4 + r;
      size_t base = ((size_t)b * 2048 + t) * 2048 + h * 128;
#pragma unroll
      for (int nf = 0; nf < 8; ++nf)
        ob[base + nf * 16 + l16] = (bf16_t)(oacc[mf][nf][r] * inv);
    }
  }
}

// ------------------------- projection GEMM ---------------------------------
__global__ __launch_bounds__(256, 2) void k_proj(
    const bf16_t* __restrict__ O, const bf16_t* __restrict__ Wp,
    float* __restrict__ Y) {
  const int K = 2048;
  __shared__ alignas(16) bf16_t As[128 * 64];
  __shared__ alignas(16) bf16_t Bs[128 * 64];
  const int tid = threadIdx.x;
  const int lane = tid & 63, wv = tid >> 6;
  const int wm = wv >> 1, wn = wv & 1;
  const int q4 = lane >> 4, l16 = lane & 15;
  const int m0 = blockIdx.x * 128, n0 = blockIdx.y * 128;

  const bf16_t* Ab = O + (size_t)m0 * K;
  const bf16_t* Wb = Wp + (size_t)n0 * K;

  f32x4 zero4 = {0.f, 0.f, 0.f, 0.f};
  f32x4 acc[4][4];
#pragma unroll
  for (int i = 0; i < 4; ++i)
#pragma unroll
    for (int j = 0; j < 4; ++j) acc[i][j] = zero4;

  for (int k0 = 0; k0 < K; k0 += 64) {
    __syncthreads();
#pragma unroll
    for (int i = 0; i < 4; ++i) {
      int ci = i * 256 + tid;
      glds16(Ab + (size_t)(ci >> 3) * K + k0 + (((ci & 7) ^ ((ci >> 3) & 7)) << 3),
             &As[(i * 256 + wv * 64) * 8]);
    }
#pragma unroll
    for (int i = 0; i < 4; ++i) {
      int ci = i * 256 + tid;
      glds16(Wb + (size_t)(ci >> 3) * K + k0 + (((ci & 7) ^ ((ci >> 3) & 7)) << 3),
             &Bs[(i * 256 + wv * 64) * 8]);
    }
    __syncthreads();
#pragma unroll
    for (int kk = 0; kk < 2; ++kk) {
      bf16x8 afrag[4], bfrag[4];
#pragma unroll
      for (int mf = 0; mf < 4; ++mf)
        afrag[mf] = *(const bf16x8*)&As[(wm * 64 + mf * 16 + l16) * 64 +
                                        ((((kk << 2) | q4) ^ (l16 & 7)) << 3)];
#pragma unroll
      for (int nf = 0; nf < 4; ++nf)
        bfrag[nf] = *(const bf16x8*)&Bs[(wn * 64 + nf * 16 + l16) * 64 +
                                        ((((kk << 2) | q4) ^ (l16 & 7)) << 3)];
#pragma unroll
      for (int mf = 0; mf < 4; ++mf)
#pragma unroll
        for (int nf = 0; nf < 4; ++nf)
          acc[mf][nf] = __builtin_amdgcn_mfma_f32_16x16x32_bf16(
              afrag[mf], bfrag[nf], acc[mf][nf], 0, 0, 0);
    }
  }
#pragma unroll
  for (int mf = 0; mf < 4; ++mf)
#pragma unroll
    for (int nf = 0; nf < 4; ++nf)
#pragma unroll
      for (int r = 0; r < 4; ++r) {
        int m = m0 + wm * 64 + mf * 16 + q4 * 4 + r;
        int n = n0 + wn * 64 + nf * 16 + l16;
        Y[(size_t)m * 2048 + n] = acc[mf][nf][r];
      }
}

// ------------------------- launch ------------------------------------------
extern "C" void kernel_launch(void* const* d_in, const int* in_sizes, int n_in,
                              void* d_out, int out_size, void* d_ws, size_t ws_size,
                              hipStream_t stream) {
  const float* x = (const float*)d_in[0];
  const float* wqkv = (const float*)d_in[1];
  const float* wproj = (const float*)d_in[2];

  float* y = (float*)d_out;
  float* kout = y + SLICE_;
  float* vout = y + 2 * SLICE_;

  char* w = (char*)d_ws;
  bf16_t* xb = (bf16_t*)w;      w += SLICE_ * 2;
  bf16_t* wqkvb = (bf16_t*)w;   w += (size_t)12582912 * 2;
  bf16_t* wprojb = (bf16_t*)w;  w += (size_t)4194304 * 2;
  bf16_t* qb = (bf16_t*)w;      w += SLICE_ * 2;  // scaled+rope'd q, (B,H,T,hd)
  bf16_t* kb = (bf16_t*)w;      w += SLICE_ * 2;  // rope'd k, (B,H,T,hd)
  bf16_t* vtb = (bf16_t*)w;     w += SLICE_ * 2;  // v, (B,H,hd,T)
  bf16_t* ob = (bf16_t*)w;      w += SLICE_ * 2;  // attn out, (B,T,C)
  float2* tab = (float2*)w;     w += (size_t)131072 * 8;
  (void)ws_size; (void)in_sizes; (void)n_in; (void)out_size;

  k_cvt<<<8192, 256, 0, stream>>>((const float4*)x, (bf16x4v*)xb, 2097152);
  k_cvt<<<12288, 256, 0, stream>>>((const float4*)wqkv, (bf16x4v*)wqkvb, 3145728);
  k_cvt<<<4096, 256, 0, stream>>>((const float4*)wproj, (bf16x4v*)wprojb, 1048576);
  k_tab<<<512, 256, 0, stream>>>(tab);

  dim3 gq(32, 48);
  k_qkv<<<gq, 256, 0, stream>>>(xb, wqkvb, tab, qb, kb, vtb, kout, vout);
  k_attn<<<512, 256, 0, stream>>>(qb, kb, vtb, ob);
  dim3 gp(32, 16);
  k_proj<<<gp, 256, 0, stream>>>(ob, wprojb, y);
}

// Round 5
// 389.416 us; speedup vs baseline: 1.6965x; 1.0330x over previous
//
#include <hip/hip_runtime.h>
#include <math.h>

// ---------------------------------------------------------------------------
// SelfAttention R7: base = R2/R6 proven structure.
//  * k_attn: T14 async-STAGE split -- K/V reg-staged, next tile's global
//    loads issued BEFORE compute of current tile (latency hides under
//    QK/softmax/PV). LDS content/layout identical; compute untouched.
//    XCD grouping reverted (R6 showed no gain -> not HBM-bound).
//  * k_cvt x3 + k_tab merged into one k_prep launch.
//  * k_qkv / k_proj unchanged (m97-structure ceiling, ~925 TF).
// ---------------------------------------------------------------------------

typedef __bf16 bf16_t;
typedef __bf16 bf16x8 __attribute__((ext_vector_type(8)));
typedef __bf16 bf16x4v __attribute__((ext_vector_type(4)));
typedef float  f32x4  __attribute__((ext_vector_type(4)));

#define B_  2
#define T_  2048
#define C_  2048
#define SLICE_ ((size_t)B_ * T_ * C_)  // 8388608

__device__ __forceinline__ void glds16(const void* g, void* l) {
  __builtin_amdgcn_global_load_lds(
      (__attribute__((address_space(1))) void*)(void*)(const_cast<void*>(g)),
      (__attribute__((address_space(3))) void*)(l), 16, 0, 0);
}

// ------------------------- fused f32->bf16 packs + rope table --------------
__global__ __launch_bounds__(256) void k_prep(
    const float4* __restrict__ x, const float4* __restrict__ wqkv,
    const float4* __restrict__ wproj, bf16x4v* __restrict__ xb,
    bf16x4v* __restrict__ wqkvb, bf16x4v* __restrict__ wprojb,
    float2* __restrict__ tab) {
  int i = blockIdx.x * 256 + threadIdx.x;
  if (i < 2097152) {
    float4 v = x[i];
    bf16x4v o;
    o[0] = (bf16_t)v.x; o[1] = (bf16_t)v.y; o[2] = (bf16_t)v.z; o[3] = (bf16_t)v.w;
    xb[i] = o;
  } else if (i < 5242880) {
    int j = i - 2097152;
    float4 v = wqkv[j];
    bf16x4v o;
    o[0] = (bf16_t)v.x; o[1] = (bf16_t)v.y; o[2] = (bf16_t)v.z; o[3] = (bf16_t)v.w;
    wqkvb[j] = o;
  } else if (i < 6291456) {
    int j = i - 5242880;
    float4 v = wproj[j];
    bf16x4v o;
    o[0] = (bf16_t)v.x; o[1] = (bf16_t)v.y; o[2] = (bf16_t)v.z; o[3] = (bf16_t)v.w;
    wprojb[j] = o;
  } else {
    int j = i - 6291456;  // 0..131071
    int t = j >> 6, jj = j & 63;
    float thf = (float)pow(10000.0, -(double)(2 * jj) / 128.0);
    float angf = (float)t * thf;
    double a = (double)angf;
    tab[j] = make_float2((float)cos(a), (float)sin(a));
  }
}

// ------------------------- QKV GEMM + RoPE epilogue ------------------------
// C[m,n] = sum_k X[m,k] W[n,k]; M=4096, N=6144, K=2048. 128x128 tile, BK=64.
// LDS tiles xor-swizzled: LDS[row, c'] = global[row, c' ^ (row&7)] (16B chunks)
__global__ __launch_bounds__(256, 2) void k_qkv(
    const bf16_t* __restrict__ X, const bf16_t* __restrict__ W,
    const float2* __restrict__ tab,
    bf16_t* __restrict__ qb, bf16_t* __restrict__ kb, bf16_t* __restrict__ vtb,
    float* __restrict__ kout, float* __restrict__ vout) {
  const int K = 2048;
  __shared__ alignas(16) bf16_t smem[17408];  // As|Bs (16384) U epilogue 128x136
  bf16_t* As = smem;
  bf16_t* Bs = smem + 8192;
  const int tid = threadIdx.x;
  const int lane = tid & 63, wv = tid >> 6;
  const int wm = wv >> 1, wn = wv & 1;
  const int q4 = lane >> 4, l16 = lane & 15;
  const int m0 = blockIdx.x * 128, n0 = blockIdx.y * 128;

  const bf16_t* Ab = X + (size_t)m0 * K;
  const bf16_t* Wb = W + (size_t)n0 * K;

  f32x4 zero4 = {0.f, 0.f, 0.f, 0.f};
  f32x4 acc[4][4];
#pragma unroll
  for (int i = 0; i < 4; ++i)
#pragma unroll
    for (int j = 0; j < 4; ++j) acc[i][j] = zero4;

  for (int k0 = 0; k0 < K; k0 += 64) {
    __syncthreads();
#pragma unroll
    for (int i = 0; i < 4; ++i) {  // 128 rows x 8 chunks
      int ci = i * 256 + tid;
      glds16(Ab + (size_t)(ci >> 3) * K + k0 + (((ci & 7) ^ ((ci >> 3) & 7)) << 3),
             &As[(i * 256 + wv * 64) * 8]);
    }
#pragma unroll
    for (int i = 0; i < 4; ++i) {
      int ci = i * 256 + tid;
      glds16(Wb + (size_t)(ci >> 3) * K + k0 + (((ci & 7) ^ ((ci >> 3) & 7)) << 3),
             &Bs[(i * 256 + wv * 64) * 8]);
    }
    __syncthreads();
#pragma unroll
    for (int kk = 0; kk < 2; ++kk) {
      bf16x8 afrag[4], bfrag[4];
#pragma unroll
      for (int mf = 0; mf < 4; ++mf)
        afrag[mf] = *(const bf16x8*)&As[(wm * 64 + mf * 16 + l16) * 64 +
                                        ((((kk << 2) | q4) ^ (l16 & 7)) << 3)];
#pragma unroll
      for (int nf = 0; nf < 4; ++nf)
        bfrag[nf] = *(const bf16x8*)&Bs[(wn * 64 + nf * 16 + l16) * 64 +
                                        ((((kk << 2) | q4) ^ (l16 & 7)) << 3)];
#pragma unroll
      for (int mf = 0; mf < 4; ++mf)
#pragma unroll
        for (int nf = 0; nf < 4; ++nf)
          acc[mf][nf] = __builtin_amdgcn_mfma_f32_16x16x32_bf16(
              afrag[mf], bfrag[nf], acc[mf][nf], 0, 0, 0);
    }
  }

  __syncthreads();  // smem reuse for epilogue staging
  const int sec = n0 >> 11;  // 0=q, 1=k, 2=v (block-uniform)
  const int t0 = m0 & 2047, bb = m0 >> 11, h = (n0 & 2047) >> 7;

  if (sec < 2) {
#pragma unroll
    for (int mf = 0; mf < 4; ++mf)
#pragma unroll
      for (int nf = 0; nf < 4; ++nf)
#pragma unroll
        for (int r = 0; r < 4; ++r) {
          int ml = wm * 64 + mf * 16 + q4 * 4 + r;
          int d = wn * 64 + nf * 16 + l16;
          float val = acc[mf][nf][r];
          float partner = __shfl_xor(val, 1);
          float2 cs = tab[(t0 + ml) * 64 + (d >> 1)];
          float rv = (d & 1) ? (val * cs.x + partner * cs.y)
                             : (val * cs.x - partner * cs.y);
          if (sec == 0) rv *= 0.08838834764831845f;  // fold 1/sqrt(hd) into q
          else kout[(size_t)(m0 + ml) * 2048 + h * 128 + d] = val;
          smem[ml * 136 + d] = (bf16_t)rv;
        }
    __syncthreads();
    bf16_t* dst = (sec == 0 ? qb : kb);
    size_t gbase = ((size_t)(bb * 16 + h) * 2048 + t0) * 128;
#pragma unroll
    for (int i = 0; i < 8; ++i) {
      int ci = i * 256 + tid, ml = ci >> 4, cc = (ci & 15) * 8;
      *(bf16x8*)(dst + gbase + (size_t)ml * 128 + cc) =
          *(const bf16x8*)&smem[ml * 136 + cc];
    }
  } else {
#pragma unroll
    for (int mf = 0; mf < 4; ++mf)
#pragma unroll
      for (int nf = 0; nf < 4; ++nf)
#pragma unroll
        for (int r = 0; r < 4; ++r) {
          int ml = wm * 64 + mf * 16 + q4 * 4 + r;
          int d = wn * 64 + nf * 16 + l16;
          float val = acc[mf][nf][r];
          vout[((size_t)(bb * 16 + h) * 2048 + t0 + ml) * 128 + d] = val;
          smem[d * 136 + ml] = (bf16_t)val;  // transpose in LDS
        }
    __syncthreads();
#pragma unroll
    for (int i = 0; i < 8; ++i) {
      int ci = i * 256 + tid, dr = ci >> 4, cc = (ci & 15) * 8;
      *(bf16x8*)(vtb + ((size_t)((bb * 16 + h) * 128 + dr)) * 2048 + t0 + cc) =
          *(const bf16x8*)&smem[dr * 136 + cc];
    }
  }
}

// ------------------------- flash attention ---------------------------------
// block = (b,h) x 128 queries, 4 waves x 32 queries. KT=64. Q in registers.
// No-max softmax: O_unnorm += exp(s) V; l += sum exp(s); normalize at end.
// T14 async-STAGE: K/V reg-staged; loads for tile t+1 issue BEFORE compute
// of tile t so HBM latency hides under MFMA/softmax.
__global__ __launch_bounds__(256, 2) void k_attn(
    const bf16_t* __restrict__ qb, const bf16_t* __restrict__ kb,
    const bf16_t* __restrict__ vtb, bf16_t* __restrict__ ob) {
  __shared__ alignas(16) bf16_t Ps[128 * 80];   // P tile, stride 80
  __shared__ alignas(16) bf16_t Ks[64 * 128];   // swizzled
  __shared__ alignas(16) bf16_t Vts[128 * 64];  // swizzled, [d][key]

  const int tid = threadIdx.x;
  const int lane = tid & 63, wv = tid >> 6;
  const int q4 = lane >> 4, l16 = lane & 15;
  const int bh = blockIdx.x >> 4;
  const int q0 = (blockIdx.x & 15) * 128;

  const bf16_t* Qg = qb + (size_t)bh * T_ * 128 + (size_t)q0 * 128;
  const bf16_t* Kg = kb + (size_t)bh * T_ * 128;
  const bf16_t* Vg = vtb + (size_t)bh * 128 * T_;

  // Q frags straight from global (one-time, pre-scaled by 1/sqrt(hd))
  bf16x8 qa[2][4];
#pragma unroll
  for (int mf = 0; mf < 2; ++mf)
#pragma unroll
    for (int kf = 0; kf < 4; ++kf)
      qa[mf][kf] = *(const bf16x8*)(Qg + (size_t)(wv * 32 + mf * 16 + l16) * 128 +
                                    kf * 32 + q4 * 8);

  f32x4 zero4 = {0.f, 0.f, 0.f, 0.f};
  float lrow[2][4];
  f32x4 oacc[2][8];
#pragma unroll
  for (int mf = 0; mf < 2; ++mf) {
#pragma unroll
    for (int r = 0; r < 4; ++r) lrow[mf][r] = 0.f;
#pragma unroll
    for (int nf = 0; nf < 8; ++nf) oacc[mf][nf] = zero4;
  }

  // ---- issue staging loads for tile 0 (K: 64x128, V: 128x64, swizzled) ----
  bf16x8 kst[4], vst[4];
#pragma unroll
  for (int i = 0; i < 4; ++i) {
    int ci = i * 256 + tid;
    kst[i] = *(const bf16x8*)(Kg + (size_t)(ci >> 4) * 128 +
                              (((ci & 15) ^ ((ci >> 4) & 7)) << 3));
    vst[i] = *(const bf16x8*)(Vg + (size_t)(ci >> 3) * T_ +
                              (((ci & 7) ^ ((ci >> 3) & 7)) << 3));
  }

  for (int key0 = 0; key0 < T_; key0 += 64) {
    __syncthreads();  // previous compute done reading Ks/Vts
#pragma unroll
    for (int i = 0; i < 4; ++i) {  // write staged regs (waits vmcnt via dep)
      int ci = i * 256 + tid;
      *(bf16x8*)&Ks[ci * 8] = kst[i];
      *(bf16x8*)&Vts[ci * 8] = vst[i];
    }
    __syncthreads();  // writes visible

    if (key0 + 64 < T_) {  // issue NEXT tile's loads; hide under compute
      const bf16_t* Kg2 = Kg + (size_t)(key0 + 64) * 128;
      const bf16_t* Vg2 = Vg + key0 + 64;
#pragma unroll
      for (int i = 0; i < 4; ++i) {
        int ci = i * 256 + tid;
        kst[i] = *(const bf16x8*)(Kg2 + (size_t)(ci >> 4) * 128 +
                                  (((ci & 15) ^ ((ci >> 4) & 7)) << 3));
        vst[i] = *(const bf16x8*)(Vg2 + (size_t)(ci >> 3) * T_ +
                                  (((ci & 7) ^ ((ci >> 3) & 7)) << 3));
      }
    }

    // S = Q K^T (pre-scaled)
    f32x4 sacc[2][4];
#pragma unroll
    for (int mf = 0; mf < 2; ++mf)
#pragma unroll
      for (int nf = 0; nf < 4; ++nf) sacc[mf][nf] = zero4;
#pragma unroll
    for (int kf = 0; kf < 4; ++kf) {
      bf16x8 bfrag[4];
#pragma unroll
      for (int nf = 0; nf < 4; ++nf)
        bfrag[nf] = *(const bf16x8*)&Ks[(nf * 16 + l16) * 128 +
                                        ((((kf << 2) | q4) ^ (l16 & 7)) << 3)];
#pragma unroll
      for (int mf = 0; mf < 2; ++mf)
#pragma unroll
        for (int nf = 0; nf < 4; ++nf)
          sacc[mf][nf] = __builtin_amdgcn_mfma_f32_16x16x32_bf16(
              qa[mf][kf], bfrag[nf], sacc[mf][nf], 0, 0, 0);
    }

    // exp + P to LDS; per-lane partial row sums (reduced after key loop)
#pragma unroll
    for (int mf = 0; mf < 2; ++mf) {
#pragma unroll
      for (int r = 0; r < 4; ++r) {
        float p0 = __expf(sacc[mf][0][r]);
        float p1 = __expf(sacc[mf][1][r]);
        float p2 = __expf(sacc[mf][2][r]);
        float p3 = __expf(sacc[mf][3][r]);
        int prow = wv * 32 + mf * 16 + q4 * 4 + r;
        Ps[prow * 80 + 0 + l16]  = (bf16_t)p0;
        Ps[prow * 80 + 16 + l16] = (bf16_t)p1;
        Ps[prow * 80 + 32 + l16] = (bf16_t)p2;
        Ps[prow * 80 + 48 + l16] = (bf16_t)p3;
        lrow[mf][r] += (p0 + p1) + (p2 + p3);
      }
    }

    // O += P V
#pragma unroll
    for (int kf2 = 0; kf2 < 2; ++kf2) {
      bf16x8 pa[2], vb[8];
#pragma unroll
      for (int mf = 0; mf < 2; ++mf)
        pa[mf] = *(const bf16x8*)&Ps[(wv * 32 + mf * 16 + l16) * 80 +
                                     kf2 * 32 + q4 * 8];
#pragma unroll
      for (int nf = 0; nf < 8; ++nf)
        vb[nf] = *(const bf16x8*)&Vts[(nf * 16 + l16) * 64 +
                                      ((((kf2 << 2) | q4) ^ (l16 & 7)) << 3)];
#pragma unroll
      for (int mf = 0; mf < 2; ++mf)
#pragma unroll
        for (int nf = 0; nf < 8; ++nf)
          oacc[mf][nf] = __builtin_amdgcn_mfma_f32_16x16x32_bf16(
              pa[mf], vb[nf], oacc[mf][nf], 0, 0, 0);
    }
  }

  // reduce l across the 16-lane row group, then normalize + store
  const int b = bh >> 4, h = bh & 15;
#pragma unroll
  for (int mf = 0; mf < 2; ++mf) {
#pragma unroll
    for (int r = 0; r < 4; ++r) {
      float l = lrow[mf][r];
      l += __shfl_xor(l, 1);
      l += __shfl_xor(l, 2);
      l += __shfl_xor(l, 4);
      l += __shfl_xor(l, 8);
      float inv = 1.f / l;
      int t = q0 + wv * 32 + mf * 16 + q4 * 4 + r;
      size_t base = ((size_t)b * 2048 + t) * 2048 + h * 128;
#pragma unroll
      for (int nf = 0; nf < 8; ++nf)
        ob[base + nf * 16 + l16] = (bf16_t)(oacc[mf][nf][r] * inv);
    }
  }
}

// ------------------------- projection GEMM ---------------------------------
__global__ __launch_bounds__(256, 2) void k_proj(
    const bf16_t* __restrict__ O, const bf16_t* __restrict__ Wp,
    float* __restrict__ Y) {
  const int K = 2048;
  __shared__ alignas(16) bf16_t As[128 * 64];
  __shared__ alignas(16) bf16_t Bs[128 * 64];
  const int tid = threadIdx.x;
  const int lane = tid & 63, wv = tid >> 6;
  const int wm = wv >> 1, wn = wv & 1;
  const int q4 = lane >> 4, l16 = lane & 15;
  const int m0 = blockIdx.x * 128, n0 = blockIdx.y * 128;

  const bf16_t* Ab = O + (size_t)m0 * K;
  const bf16_t* Wb = Wp + (size_t)n0 * K;

  f32x4 zero4 = {0.f, 0.f, 0.f, 0.f};
  f32x4 acc[4][4];
#pragma unroll
  for (int i = 0; i < 4; ++i)
#pragma unroll
    for (int j = 0; j < 4; ++j) acc[i][j] = zero4;

  for (int k0 = 0; k0 < K; k0 += 64) {
    __syncthreads();
#pragma unroll
    for (int i = 0; i < 4; ++i) {
      int ci = i * 256 + tid;
      glds16(Ab + (size_t)(ci >> 3) * K + k0 + (((ci & 7) ^ ((ci >> 3) & 7)) << 3),
             &As[(i * 256 + wv * 64) * 8]);
    }
#pragma unroll
    for (int i = 0; i < 4; ++i) {
      int ci = i * 256 + tid;
      glds16(Wb + (size_t)(ci >> 3) * K + k0 + (((ci & 7) ^ ((ci >> 3) & 7)) << 3),
             &Bs[(i * 256 + wv * 64) * 8]);
    }
    __syncthreads();
#pragma unroll
    for (int kk = 0; kk < 2; ++kk) {
      bf16x8 afrag[4], bfrag[4];
#pragma unroll
      for (int mf = 0; mf < 4; ++mf)
        afrag[mf] = *(const bf16x8*)&As[(wm * 64 + mf * 16 + l16) * 64 +
                                        ((((kk << 2) | q4) ^ (l16 & 7)) << 3)];
#pragma unroll
      for (int nf = 0; nf < 4; ++nf)
        bfrag[nf] = *(const bf16x8*)&Bs[(wn * 64 + nf * 16 + l16) * 64 +
                                        ((((kk << 2) | q4) ^ (l16 & 7)) << 3)];
#pragma unroll
      for (int mf = 0; mf < 4; ++mf)
#pragma unroll
        for (int nf = 0; nf < 4; ++nf)
          acc[mf][nf] = __builtin_amdgcn_mfma_f32_16x16x32_bf16(
              afrag[mf], bfrag[nf], acc[mf][nf], 0, 0, 0);
    }
  }
#pragma unroll
  for (int mf = 0; mf < 4; ++mf)
#pragma unroll
    for (int nf = 0; nf < 4; ++nf)
#pragma unroll
      for (int r = 0; r < 4; ++r) {
        int m = m0 + wm * 64 + mf * 16 + q4 * 4 + r;
        int n = n0 + wn * 64 + nf * 16 + l16;
        Y[(size_t)m * 2048 + n] = acc[mf][nf][r];
      }
}

// ------------------------- launch ------------------------------------------
extern "C" void kernel_launch(void* const* d_in, const int* in_sizes, int n_in,
                              void* d_out, int out_size, void* d_ws, size_t ws_size,
                              hipStream_t stream) {
  const float* x = (const float*)d_in[0];
  const float* wqkv = (const float*)d_in[1];
  const float* wproj = (const float*)d_in[2];

  float* y = (float*)d_out;
  float* kout = y + SLICE_;
  float* vout = y + 2 * SLICE_;

  char* w = (char*)d_ws;
  bf16_t* xb = (bf16_t*)w;      w += SLICE_ * 2;
  bf16_t* wqkvb = (bf16_t*)w;   w += (size_t)12582912 * 2;
  bf16_t* wprojb = (bf16_t*)w;  w += (size_t)4194304 * 2;
  bf16_t* qb = (bf16_t*)w;      w += SLICE_ * 2;  // scaled+rope'd q, (B,H,T,hd)
  bf16_t* kb = (bf16_t*)w;      w += SLICE_ * 2;  // rope'd k, (B,H,T,hd)
  bf16_t* vtb = (bf16_t*)w;     w += SLICE_ * 2;  // v, (B,H,hd,T)
  bf16_t* ob = (bf16_t*)w;      w += SLICE_ * 2;  // attn out, (B,T,C)
  float2* tab = (float2*)w;     w += (size_t)131072 * 8;
  (void)ws_size; (void)in_sizes; (void)n_in; (void)out_size;

  // 6291456 cvt float4s + 131072 tab entries = 6422528 threads = 25088 blocks
  k_prep<<<25088, 256, 0, stream>>>((const float4*)x, (const float4*)wqkv,
                                    (const float4*)wproj, (bf16x4v*)xb,
                                    (bf16x4v*)wqkvb, (bf16x4v*)wprojb, tab);

  dim3 gq(32, 48);
  k_qkv<<<gq, 256, 0, stream>>>(xb, wqkvb, tab, qb, kb, vtb, kout, vout);
  k_attn<<<512, 256, 0, stream>>>(qb, kb, vtb, ob);
  dim3 gp(32, 16);
  k_proj<<<gp, 256, 0, stream>>>(ob, wprojb, y);
}